// Round 1
// baseline (451.822 us; speedup 1.0000x reference)
//
#include <hip/hip_runtime.h>
#include <hip/hip_bf16.h>

// Problem constants (match reference)
#define NN 100000   // nodes
#define NE 640000   // edges
#define NG 64       // graphs
#define BN_EPS 1e-5f

#define BS 256      // block size
#define PNPB 256    // nodes per block in pool
#define CAP 32      // fixed CSR slots per row (P(indeg>=32) ~ 1e-9; wrap-guarded)

// fused1: interleaved heterogeneous grid, 4 scatter : 5 gemm per 9-block group
// (R15-proven config). Locked-in lessons: R16 (4-edge/thread scatter) regressed;
// R17 (head fusion w/ device fences) cost 27us; R19 (4-wide predicated MLP
// gathers) cost 15us.
// R20 (this round): plane-partitioned intermediate tables ([FO/16][N][16] bf16)
// + XCD-pinned gather kernels so each random-gather pass works on a 3.2 MB
// plane that fits a per-XCD 4 MB L2 (theory: 287 MB of random gathers were
// L3-bound). propCG split into propCp (plane-split, h in-place over S) +
// gemmp (standalone MFMA). Numerics identical to R18.
#define NB_SCAT 1250                 // cdiv(NE, 512)
#define NB_G1   1563
#define NB_F1   (313 * 9)            // 2817

#define BPP 782                      // blocks per plane: cdiv(2*NN, 256)
#define GRID_NP4 3128                // 8 * 391  (4 planes, XCD-pair each)
#define GRID_NP2 1568                // 8 * 196  (2 planes, XCD-quad each)
#define GRID_NP1 782

typedef __attribute__((ext_vector_type(8))) unsigned short ushort8_t;
typedef __attribute__((ext_vector_type(4))) unsigned short ushort4_t;
typedef __attribute__((ext_vector_type(8))) short bf16x8_t;    // MFMA A/B frag (4 VGPR)
typedef __attribute__((ext_vector_type(4))) float floatx4_t;   // MFMA C/D frag

static inline int cdiv(long long a, int b) { return (int)((a + b - 1) / b); }

__device__ __forceinline__ float bf2f(unsigned short u) {
    union { unsigned int i; float f; } c; c.i = ((unsigned int)u) << 16; return c.f;
}
__device__ __forceinline__ unsigned short f2bf(float f) {   // RNE
    unsigned int u = __float_as_uint(f);
    u += 0x7fffu + ((u >> 16) & 1u);
    return (unsigned short)(u >> 16);
}

// ---- prepB piece: Bcat = [W2 | W1 | W0-W2] (FI x 3FO) in MFMA B-fragment layout ----
template <int FI, int FO>
__device__ __forceinline__ void prep_one(const float* __restrict__ W,
                                         unsigned short* __restrict__ Bfrag, int id) {
    constexpr int NS = FI / 32;
    int lane = id & 63;
    int s = (id >> 6) % NS;
    int t = (id >> 6) / NS;
    int n = t * 16 + (lane & 15);
    int kbase = s * 32 + (lane >> 4) * 8;
    int sec = n / FO;        // 0 -> W2, 1 -> W1, 2 -> W0 - W2
    int nc  = n % FO;
    ushort8_t out;
#pragma unroll
    for (int j = 0; j < 8; j++) {
        int k = kbase + j;
        float v;
        if (sec == 0)      v = W[(size_t)(2 * FI + k) * FO + nc];
        else if (sec == 1) v = W[(size_t)(1 * FI + k) * FO + nc];
        else               v = W[(size_t)(0 * FI + k) * FO + nc]
                             - W[(size_t)(2 * FI + k) * FO + nc];
        out[j] = f2bf(v);
    }
    *(ushort8_t*)(Bfrag + (size_t)id * 8) = out;
}

// Separate launch, stream-ordered BEFORE any consumer of Bf1/2/3 (R13 race lesson).
__global__ void prepB_all_kernel(const float* __restrict__ W1, const float* __restrict__ W2,
                                 const float* __restrict__ W3,
                                 unsigned short* __restrict__ Bf1,
                                 unsigned short* __restrict__ Bf2,
                                 unsigned short* __restrict__ Bf3) {
    int id = blockIdx.x * blockDim.x + threadIdx.x;
    if (id < 3072)      prep_one<128, 64>(W1, Bf1, id);            // 12*4*64
    else if (id < 3840) prep_one<64, 32>(W2, Bf2, id - 3072);      //  6*2*64
    else if (id < 4032) prep_one<32, 16>(W3, Bf3, id - 3840);      //  3*1*64
}

// ---- fused1: interleaved [scatter | gemm layer-1], NO LDS ----
// Epilogue now writes U/T/S in PLANAR layout: table[plane][N][16] bf16.
__global__ __launch_bounds__(256) void fused1_kernel(
        const int* __restrict__ src, const int* __restrict__ dst,
        int* __restrict__ fill, int* __restrict__ deg_o, int* __restrict__ col,
        const unsigned short* __restrict__ Bf1,
        const float* __restrict__ x, unsigned short* __restrict__ Tbf,
        unsigned short* __restrict__ Sbf, unsigned short* __restrict__ Ubf,
        int E, int N) {
    const int g = blockIdx.x / 9;
    const int r = blockIdx.x % 9;
    if (r < 4) {
        // ------- scatter: 2 edges/thread (R15-proven) -------
        int sid = g * 4 + r;
        if (sid >= NB_SCAT) return;
        int e0 = (sid * 256 + threadIdx.x) * 2;
#pragma unroll
        for (int q = 0; q < 2; q++) {
            int e = e0 + q;
            if (e < E) {
                int s = src[e], d = dst[e];
                if (s != d) {
                    atomicAdd(&deg_o[s], 1);
                    int pos = atomicAdd(&fill[d], 1) & (CAP - 1);   // wrap guard
                    col[(size_t)d * CAP + pos] = s;
                }
            }
        }
        return;
    }
    // ------- gemm layer-1 path (direct-global B, latency hides in atomic shadow) -------
    int gblk = g * 5 + (r - 4);
    if (gblk >= NB_G1) return;
    constexpr int NT = 12;   // 3*64/16
    constexpr int NS = 4;    // 128/32
    const int lane = threadIdx.x & 63;
    const int wave = threadIdx.x >> 6;
    const int m0   = gblk * 64 + wave * 16;
    const int quad = lane >> 4;
    const int mrow = m0 + (lane & 15);

    floatx4_t acc[NT];
#pragma unroll
    for (int t = 0; t < NT; t++) acc[t] = (floatx4_t){0.f, 0.f, 0.f, 0.f};

#pragma unroll
    for (int s = 0; s < NS; s++) {
        bf16x8_t a;
        if (mrow < N) {
            const float* ap = x + (size_t)mrow * 128 + s * 32 + quad * 8;
            float4 a0 = *(const float4*)(ap);
            float4 a1 = *(const float4*)(ap + 4);
            a[0] = (short)f2bf(a0.x); a[1] = (short)f2bf(a0.y);
            a[2] = (short)f2bf(a0.z); a[3] = (short)f2bf(a0.w);
            a[4] = (short)f2bf(a1.x); a[5] = (short)f2bf(a1.y);
            a[6] = (short)f2bf(a1.z); a[7] = (short)f2bf(a1.w);
        } else {
            a = (bf16x8_t){0, 0, 0, 0, 0, 0, 0, 0};
        }
#pragma unroll
        for (int t = 0; t < NT; t++) {
            bf16x8_t b = *(const bf16x8_t*)(Bf1 + ((size_t)(t * NS + s) * 64 + lane) * 8);
            acc[t] = __builtin_amdgcn_mfma_f32_16x16x32_bf16(a, b, acc[t], 0, 0, 0);
        }
    }
    // C/D layout: col = lane&15, row = quad*4 + reg   [verified m89/m91]
    // Planar epilogue: sec = t/4 selects table, tp = t&3 is the 16-col plane.
#pragma unroll
    for (int t = 0; t < NT; t++) {
        int sec = t >> 2;
        int tp  = t & 3;
        int nc16 = lane & 15;
#pragma unroll
        for (int r2 = 0; r2 < 4; r2++) {
            int m = m0 + quad * 4 + r2;
            if (m >= N) continue;
            unsigned short v = f2bf(acc[t][r2]);
            size_t o = ((size_t)tp * N + m) * 16 + nc16;
            if (sec == 0)      Ubf[o] = v;
            else if (sec == 1) Tbf[o] = v;
            else               Sbf[o] = v;
        }
    }
}

// ---- rdeg: rsqrt table so props do 1 mul/edge ----
__global__ void rdeg_kernel(const int* __restrict__ deg_o, float* __restrict__ rdeg, int N) {
    int i = blockIdx.x * blockDim.x + threadIdx.x;
    if (i < N) {
        int d = deg_o[i];
        rdeg[i] = (d > 0) ? rsqrtf((float)d) : 0.0f;
    }
}

// ---- XCD-pinned plane mapping helper ----
// Blocks dispatch round-robin over 8 XCDs (blockIdx % 8). Pinning plane p to a
// fixed XCD subset keeps that plane's 3.2 MB table resident in those L2s.
template <int NP>
__device__ __forceinline__ bool plane_map(int bid, int tid, int N, int& p, int& i, int& h) {
    int j;
    if constexpr (NP == 4) {
        int slot = bid & 7, grp = bid >> 3;
        p = slot >> 1; j = grp * 2 + (slot & 1);           // XCD pair per plane
    } else if constexpr (NP == 2) {
        int slot = bid & 7, grp = bid >> 3;
        p = slot >> 2; j = grp * 4 + (slot & 3);           // XCD quad per plane
        if (j >= BPP) return false;
    } else {
        p = 0; j = bid;
    }
    int t2 = j * 256 + tid;
    i = t2 >> 1;
    if (i >= N) return false;
    h = (t2 & 1) * 8;
    return true;
}

// ---- propA8p: Obf[p][i] = bf16( T[p][i] + 2 * sum_n w(n)*U[p][col[n]] ), planar ----
template <int FO>
__global__ __launch_bounds__(256) void propA8p_kernel(
        const unsigned short* __restrict__ Ubf,   // planar [FO/16][N][16]
        const unsigned short* __restrict__ Tbf,   // planar
        const int* __restrict__ fill, const float* __restrict__ rdeg,
        const int* __restrict__ col,
        unsigned short* __restrict__ Obf, int N) {
    constexpr int NP = FO / 16;
    int p, i, h;
    if (!plane_map<NP>((int)blockIdx.x, (int)threadIdx.x, N, p, i, h)) return;
    const unsigned short* Up = Ubf + (size_t)p * N * 16;
    int beg = i * CAP;
    int end = beg + min(fill[i], CAP);
    float di = -rdeg[i];
    float acc[8] = {0.f, 0.f, 0.f, 0.f, 0.f, 0.f, 0.f, 0.f};
    int pp = beg;
    for (; pp + 2 <= end; pp += 2) {
        int s0 = __builtin_nontemporal_load(&col[pp]);
        int s1 = __builtin_nontemporal_load(&col[pp + 1]);
        float w0 = di * rdeg[s0], w1 = di * rdeg[s1];
        ushort8_t u0 = *(const ushort8_t*)(Up + (size_t)s0 * 16 + h);
        ushort8_t u1 = *(const ushort8_t*)(Up + (size_t)s1 * 16 + h);
#pragma unroll
        for (int jj = 0; jj < 8; jj++) {
            acc[jj] = fmaf(w0, bf2f(u0[jj]), acc[jj]);
            acc[jj] = fmaf(w1, bf2f(u1[jj]), acc[jj]);
        }
    }
    if (pp < end) {
        int s0 = __builtin_nontemporal_load(&col[pp]);
        float w0 = di * rdeg[s0];
        ushort8_t u0 = *(const ushort8_t*)(Up + (size_t)s0 * 16 + h);
#pragma unroll
        for (int jj = 0; jj < 8; jj++) acc[jj] = fmaf(w0, bf2f(u0[jj]), acc[jj]);
    }
    ushort8_t tv = __builtin_nontemporal_load(
        (const ushort8_t*)(Tbf + ((size_t)p * N + i) * 16 + h));
    ushort8_t o;
#pragma unroll
    for (int jj = 0; jj < 8; jj++) o[jj] = f2bf(bf2f(tv[jj]) + 2.f * acc[jj]);
    *(ushort8_t*)(Obf + ((size_t)p * N + i) * 16 + h) = o;
}

// ---- propCp: h[p][i] = leakyrelu(BN(S[p][i] + sum_n w(n)*B[p][col[n]])), planar ----
// h overwrites S IN-PLACE (each 16B slice owned by exactly one thread: read
// before write, no cross-thread hazard).
template <int FI>
__global__ __launch_bounds__(256) void propCp_kernel(
        const unsigned short* __restrict__ Bbf,   // gather source, planar [FI/16][N][16]
        unsigned short* __restrict__ Sbf,         // S in / h out, planar
        const int* __restrict__ fill, const float* __restrict__ rdeg,
        const int* __restrict__ col,
        const float* __restrict__ b, const float* __restrict__ g,
        const float* __restrict__ be, const float* __restrict__ m,
        const float* __restrict__ vv, int N) {
    constexpr int NP = FI / 16;
    int p, i, h;
    if (!plane_map<NP>((int)blockIdx.x, (int)threadIdx.x, N, p, i, h)) return;
    const unsigned short* Bp = Bbf + (size_t)p * N * 16;
    unsigned short* Sp = Sbf + (size_t)p * N * 16;
    int beg = i * CAP;
    int end = beg + min(fill[i], CAP);
    float di = -rdeg[i];
    float acc[8] = {0.f, 0.f, 0.f, 0.f, 0.f, 0.f, 0.f, 0.f};
    int pp = beg;
    for (; pp + 2 <= end; pp += 2) {
        int s0 = __builtin_nontemporal_load(&col[pp]);
        int s1 = __builtin_nontemporal_load(&col[pp + 1]);
        float w0 = di * rdeg[s0], w1 = di * rdeg[s1];
        ushort8_t u0 = *(const ushort8_t*)(Bp + (size_t)s0 * 16 + h);
        ushort8_t u1 = *(const ushort8_t*)(Bp + (size_t)s1 * 16 + h);
#pragma unroll
        for (int jj = 0; jj < 8; jj++) {
            acc[jj] = fmaf(w0, bf2f(u0[jj]), acc[jj]);
            acc[jj] = fmaf(w1, bf2f(u1[jj]), acc[jj]);
        }
    }
    if (pp < end) {
        int s0 = __builtin_nontemporal_load(&col[pp]);
        float w0 = di * rdeg[s0];
        ushort8_t u0 = *(const ushort8_t*)(Bp + (size_t)s0 * 16 + h);
#pragma unroll
        for (int jj = 0; jj < 8; jj++) acc[jj] = fmaf(w0, bf2f(u0[jj]), acc[jj]);
    }
    ushort8_t sv = *(const ushort8_t*)(Sp + (size_t)i * 16 + h);
    ushort8_t o;
#pragma unroll
    for (int jj = 0; jj < 8; jj++) {
        int f = p * 16 + h + jj;
        float A  = g[f] * rsqrtf(vv[f] + BN_EPS);
        float Bc = be[f] - (m[f] - b[f]) * A;
        float y  = (bf2f(sv[jj]) + acc[jj]) * A + Bc;
        y = y > 0.0f ? y : 0.01f * y;
        o[jj] = f2bf(y);
    }
    *(ushort8_t*)(Sp + (size_t)i * 16 + h) = o;
}

// ---- gemmp<FI,FO>: standalone MFMA, A from planar h, B frags LDS-staged ----
template <int FI, int FO>
__global__ __launch_bounds__(256) void gemmp_kernel(
        const unsigned short* __restrict__ hbf,    // planar [FI/16][N][16]
        const unsigned short* __restrict__ Bfrag,  // FI->FO fragments
        unsigned short* __restrict__ Tout, unsigned short* __restrict__ Sout,
        unsigned short* __restrict__ Uout, int N) {
    constexpr int NT = 3 * FO / 16;
    constexpr int NS = FI / 32;
    constexpr int NFRAG = NT * NS;
    constexpr int CPP = FO / 16;    // planes per output section
    __shared__ ushort8_t bl[NFRAG * 64];

    for (int q = threadIdx.x; q < NFRAG * 64; q += 256)
        bl[q] = ((const ushort8_t*)Bfrag)[q];
    __syncthreads();

    const int lane = threadIdx.x & 63;
    const int wave = threadIdx.x >> 6;
    const int quad = lane >> 4;
    const int m0   = blockIdx.x * 64;
    const int mrow = m0 + wave * 16 + (lane & 15);

    floatx4_t acc[NT];
#pragma unroll
    for (int t = 0; t < NT; t++) acc[t] = (floatx4_t){0.f, 0.f, 0.f, 0.f};

#pragma unroll
    for (int s = 0; s < NS; s++) {
        bf16x8_t a;
        if (mrow < N) {
            // feats s*32 + quad*8  ->  plane 2s + (quad>>1), offset (quad&1)*8
            a = *(const bf16x8_t*)&hbf[((size_t)(2 * s + (quad >> 1)) * N + mrow) * 16
                                       + (quad & 1) * 8];
        } else {
            a = (bf16x8_t){0, 0, 0, 0, 0, 0, 0, 0};
        }
#pragma unroll
        for (int t = 0; t < NT; t++) {
            bf16x8_t bfr = *(const bf16x8_t*)&bl[(t * NS + s) * 64 + lane];
            acc[t] = __builtin_amdgcn_mfma_f32_16x16x32_bf16(a, bfr, acc[t], 0, 0, 0);
        }
    }
#pragma unroll
    for (int t = 0; t < NT; t++) {
        int sec = t / CPP;
        int tp  = t % CPP;
        int nc16 = lane & 15;
#pragma unroll
        for (int r = 0; r < 4; r++) {
            int mm = m0 + wave * 16 + quad * 4 + r;
            if (mm >= N) continue;
            unsigned short v = f2bf(acc[t][r]);
            size_t o = ((size_t)tp * N + mm) * 16 + nc16;
            if (sec == 0)      Uout[o] = v;
            else if (sec == 1) Tout[o] = v;
            else               Sout[o] = v;
        }
    }
}

// ---- poolC: fused [propC layer-3 (w16, planar==row-major) -> LDS h3] + [mean pool] ----
__global__ __launch_bounds__(256) void poolC_kernel(
        const unsigned short* __restrict__ Bbf,   // propA8p<16> output (1 plane == row-major)
        const unsigned short* __restrict__ Sbf,   // S3 (1 plane == row-major)
        const int* __restrict__ fill, const float* __restrict__ rdeg,
        const int* __restrict__ col,
        const float* __restrict__ b, const float* __restrict__ g,
        const float* __restrict__ be, const float* __restrict__ m,
        const float* __restrict__ vv,
        const int* __restrict__ batch,
        float* __restrict__ pool, float* __restrict__ cnt, int N) {
    __shared__ unsigned short h_lds[PNPB * 16];   // 8 KB
    __shared__ float sp[NG * 16];
    __shared__ float sc[NG];
    const int t = threadIdx.x;
    for (int i = t; i < NG * 16; i += 256) sp[i] = 0.f;
    for (int i = t; i < NG; i += 256) sc[i] = 0.f;

    const int base = blockIdx.x * PNPB;
    // ---- phase 1: propC<16> for rows base..base+255 -> h_lds ----
    for (int w = t; w < PNPB * 2; w += 256) {
        int ii = w >> 1;
        int i  = base + ii;
        int c  = (w & 1) * 8;
        ushort8_t o = (ushort8_t){0, 0, 0, 0, 0, 0, 0, 0};
        if (i < N) {
            int beg = i * CAP;
            int end = beg + min(fill[i], CAP);
            float di = -rdeg[i];
            float acc[8] = {0.f, 0.f, 0.f, 0.f, 0.f, 0.f, 0.f, 0.f};
            int p = beg;
            for (; p + 2 <= end; p += 2) {
                int s0 = col[p], s1 = col[p + 1];
                float w0 = di * rdeg[s0], w1 = di * rdeg[s1];
                ushort8_t u0 = *(const ushort8_t*)(Bbf + (size_t)s0 * 16 + c);
                ushort8_t u1 = *(const ushort8_t*)(Bbf + (size_t)s1 * 16 + c);
#pragma unroll
                for (int j = 0; j < 8; j++) {
                    acc[j] = fmaf(w0, bf2f(u0[j]), acc[j]);
                    acc[j] = fmaf(w1, bf2f(u1[j]), acc[j]);
                }
            }
            if (p < end) {
                int s0 = col[p];
                float w0 = di * rdeg[s0];
                ushort8_t u0 = *(const ushort8_t*)(Bbf + (size_t)s0 * 16 + c);
#pragma unroll
                for (int j = 0; j < 8; j++) acc[j] = fmaf(w0, bf2f(u0[j]), acc[j]);
            }
            ushort8_t sv = *(const ushort8_t*)(Sbf + (size_t)i * 16 + c);
#pragma unroll
            for (int j = 0; j < 8; j++) {
                int f = c + j;
                float A = g[f] * rsqrtf(vv[f] + BN_EPS);
                float B = be[f] - (m[f] - b[f]) * A;
                float y = (bf2f(sv[j]) + acc[j]) * A + B;
                y = y > 0.0f ? y : 0.01f * y;
                o[j] = f2bf(y);
            }
        }
        *(ushort8_t*)&h_lds[ii * 16 + c] = o;
    }
    __syncthreads();

    // ---- phase 2: pool from LDS ----
    const int f4 = (t & 3) * 4;      // feature quad
    const int nl = t >> 2;           // node lane 0..63
    const int nEnd = min(base + PNPB, N);
    float4 acc = make_float4(0.f, 0.f, 0.f, 0.f);
    float cacc = 0.f;
    int gcur = -1;
    for (int n = base + nl; n < nEnd; n += 64) {
        int gi = batch[n];
        if (gi != gcur) {
            if (gcur >= 0) {
                atomicAdd(&sp[gcur * 16 + f4 + 0], acc.x);
                atomicAdd(&sp[gcur * 16 + f4 + 1], acc.y);
                atomicAdd(&sp[gcur * 16 + f4 + 2], acc.z);
                atomicAdd(&sp[gcur * 16 + f4 + 3], acc.w);
                if (f4 == 0) atomicAdd(&sc[gcur], cacc);
            }
            gcur = gi; acc = make_float4(0.f, 0.f, 0.f, 0.f); cacc = 0.f;
        }
        ushort4_t hv = *(const ushort4_t*)&h_lds[(n - base) * 16 + f4];
        acc.x += bf2f(hv.x); acc.y += bf2f(hv.y);
        acc.z += bf2f(hv.z); acc.w += bf2f(hv.w);
        cacc += 1.f;
    }
    if (gcur >= 0) {
        atomicAdd(&sp[gcur * 16 + f4 + 0], acc.x);
        atomicAdd(&sp[gcur * 16 + f4 + 1], acc.y);
        atomicAdd(&sp[gcur * 16 + f4 + 2], acc.z);
        atomicAdd(&sp[gcur * 16 + f4 + 3], acc.w);
        if (f4 == 0) atomicAdd(&sc[gcur], cacc);
    }
    __syncthreads();
    for (int i = t; i < NG * 16; i += 256)
        if (sp[i] != 0.f) unsafeAtomicAdd(&pool[i], sp[i]);
    for (int i = t; i < NG; i += 256)
        if (sc[i] != 0.f) unsafeAtomicAdd(&cnt[i], sc[i]);
}

// ---------------- final linear head ----------------
__global__ void final_kernel(const float* __restrict__ pool, const float* __restrict__ cnt,
                             const float* __restrict__ lw, const float* __restrict__ lb,
                             float* __restrict__ out) {
    int idx = threadIdx.x;
    if (idx >= NG * 2) return;
    int g = idx >> 1;
    int c = idx & 1;
    float inv = 1.0f / fmaxf(cnt[g], 1.0f);
    float acc = 0.0f;
#pragma unroll
    for (int f = 0; f < 16; f++) acc += pool[g * 16 + f] * lw[c * 16 + f];
    out[idx] = acc * inv + lb[c];
}

extern "C" void kernel_launch(void* const* d_in, const int* in_sizes, int n_in,
                              void* d_out, int out_size, void* d_ws, size_t ws_size,
                              hipStream_t stream) {
    const float* x    = (const float*)d_in[0];
    const int*   ei   = (const int*)d_in[1];
    const int*   batch= (const int*)d_in[2];
    const float* W1 = (const float*)d_in[3];
    const float* b1 = (const float*)d_in[4];
    const float* g1 = (const float*)d_in[5];
    const float* be1= (const float*)d_in[6];
    const float* m1 = (const float*)d_in[7];
    const float* v1 = (const float*)d_in[8];
    const float* W2 = (const float*)d_in[9];
    const float* b2 = (const float*)d_in[10];
    const float* g2 = (const float*)d_in[11];
    const float* be2= (const float*)d_in[12];
    const float* m2 = (const float*)d_in[13];
    const float* v2 = (const float*)d_in[14];
    const float* W3 = (const float*)d_in[15];
    const float* b3 = (const float*)d_in[16];
    const float* g3 = (const float*)d_in[17];
    const float* be3= (const float*)d_in[18];
    const float* m3 = (const float*)d_in[19];
    const float* v3 = (const float*)d_in[20];
    const float* lw = (const float*)d_in[21];
    const float* lb = (const float*)d_in[22];

    const int* src = ei;            // edge_index[0]
    const int* dst = ei + NE;       // edge_index[1]

    float* ws = (float*)d_ws;
    // ---- workspace layout (4-byte units, 16B-aligned; ~62 MB total) ----
    size_t off = 0;
    int*   fill  = (int*)(ws + off); off += NN;    // in-degree / slot counters
    int*   deg_o = (int*)(ws + off); off += NN;    // out-degree
    float* pool  = ws + off; off += NG * 16;
    float* cnt   = ws + off; off += NG;
    size_t zero_bytes = off * sizeof(float);       // one memset covers all of the above
    float* rdeg  = ws + off; off += NN;            // rsqrt(deg_o) table
    int*   col   = (int*)(ws + off); off += (size_t)NN * CAP;  // fixed-stride CSR cols
    unsigned short* Tbf  = (unsigned short*)(ws + off); off += (size_t)NN * 32;  // NN*64 bf16 planar
    unsigned short* Ubf  = (unsigned short*)(ws + off); off += (size_t)NN * 32;
    unsigned short* Bbbf = (unsigned short*)(ws + off); off += (size_t)NN * 32;
    unsigned short* S1bf = (unsigned short*)(ws + off); off += (size_t)NN * 32;  // S1/h1 (w64, in-place)
    unsigned short* S2bf = (unsigned short*)(ws + off); off += (size_t)NN * 16;  // S2/h2 (w32, in-place)
    unsigned short* S3bf = (unsigned short*)(ws + off); off += (size_t)NN * 8;   // S3 (w16)
    unsigned short* Bf1  = (unsigned short*)(ws + off); off += 12288;  // 24576 bf16
    unsigned short* Bf2  = (unsigned short*)(ws + off); off += 3072;   //  6144 bf16
    unsigned short* Bf3  = (unsigned short*)(ws + off); off += 768;    //  1536 bf16

    hipMemsetAsync(ws, 0, zero_bytes, stream);

    // ---- prepB first (stream-ordered: Bf1 complete before fused1's gemm blocks) ----
    prepB_all_kernel<<<16, BS, 0, stream>>>(W1, W2, W3, Bf1, Bf2, Bf3);

    // ---- fused: interleaved CSR scatter + gemm layer-1 (planar U/T/S out) ----
    fused1_kernel<<<NB_F1, 256, 0, stream>>>(
        src, dst, fill, deg_o, col, Bf1, x, Tbf, S1bf, Ubf, NE, NN);

    // ---- rsqrt(deg) table ----
    rdeg_kernel<<<cdiv(NN, BS), BS, 0, stream>>>(deg_o, rdeg, NN);

    // ---- layer 1: propA (XCD-pinned planes), propC (pinned, h1 in-place), gemm ----
    propA8p_kernel<64><<<GRID_NP4, BS, 0, stream>>>(Ubf, Tbf, fill, rdeg, col, Bbbf, NN);
    propCp_kernel<64><<<GRID_NP4, BS, 0, stream>>>(Bbbf, S1bf, fill, rdeg, col,
                                                   b1, g1, be1, m1, v1, NN);
    gemmp_kernel<64, 32><<<cdiv(NN, 64), BS, 0, stream>>>(S1bf, Bf2, Tbf, S2bf, Ubf, NN);

    // ---- layer 2 ----
    propA8p_kernel<32><<<GRID_NP2, BS, 0, stream>>>(Ubf, Tbf, fill, rdeg, col, Bbbf, NN);
    propCp_kernel<32><<<GRID_NP2, BS, 0, stream>>>(Bbbf, S2bf, fill, rdeg, col,
                                                   b2, g2, be2, m2, v2, NN);
    gemmp_kernel<32, 16><<<cdiv(NN, 64), BS, 0, stream>>>(S2bf, Bf3, Tbf, S3bf, Ubf, NN);

    // ---- layer 3: propA, then fused [propC3 + pool] ----
    propA8p_kernel<16><<<GRID_NP1, BS, 0, stream>>>(Ubf, Tbf, fill, rdeg, col, Bbbf, NN);
    poolC_kernel<<<cdiv(NN, PNPB), 256, 0, stream>>>(
        Bbbf, S3bf, fill, rdeg, col, b3, g3, be3, m3, v3,
        batch, pool, cnt, NN);

    // ---- head ----
    final_kernel<<<1, 128, 0, stream>>>(pool, cnt, lw, lb, (float*)d_out);
}

// Round 2
// 327.721 us; speedup vs baseline: 1.3787x; 1.3787x over previous
//
#include <hip/hip_runtime.h>
#include <hip/hip_bf16.h>

// Problem constants (match reference)
#define NN 100000   // nodes
#define NE 640000   // edges
#define NG 64       // graphs
#define BN_EPS 1e-5f

#define BS 256      // block size
#define PNPB 256    // nodes per block in pool
#define CAP 32      // fixed CSR slots per row (P(indeg>=32) ~ 1e-9; wrap-guarded)

// fused1: interleaved heterogeneous grid, 4 scatter : 5 gemm per 9-block group
// (R15-proven config). Locked-in lessons: R16 (4-edge/thread scatter) regressed;
// R17 (head fusion w/ device fences) cost 27us; R19 (4-wide predicated MLP
// gathers) cost 15us; R20 (planar tables + XCD-pinned gathers) cost 130us --
// plane-split re-reads the col stream NPx and broke fused1 store coalescing;
// gathers are NOT L3-BW-bound.
// R21 (this round): R18 structure + 4-deep BRANCHLESS gather unroll (col is
// zero-initialized so int4 slot loads past fill[] are safe; tail gathers hit
// row 0 = L1-hot). Theory: gather passes are latency-bound (all counters far
// from ceilings); double the in-flight gathers per thread.
#define NB_SCAT 1250                 // cdiv(NE, 512)
#define NB_G1   1563
#define NB_F1   (313 * 9)            // 2817

typedef __attribute__((ext_vector_type(8))) unsigned short ushort8_t;
typedef __attribute__((ext_vector_type(4))) unsigned short ushort4_t;
typedef __attribute__((ext_vector_type(8))) short bf16x8_t;    // MFMA A/B frag (4 VGPR)
typedef __attribute__((ext_vector_type(4))) float floatx4_t;   // MFMA C/D frag

static inline int cdiv(long long a, int b) { return (int)((a + b - 1) / b); }

__device__ __forceinline__ float bf2f(unsigned short u) {
    union { unsigned int i; float f; } c; c.i = ((unsigned int)u) << 16; return c.f;
}
__device__ __forceinline__ unsigned short f2bf(float f) {   // RNE
    unsigned int u = __float_as_uint(f);
    u += 0x7fffu + ((u >> 16) & 1u);
    return (unsigned short)(u >> 16);
}

// ---- prepB piece: Bcat = [W2 | W1 | W0-W2] (FI x 3FO) in MFMA B-fragment layout ----
template <int FI, int FO>
__device__ __forceinline__ void prep_one(const float* __restrict__ W,
                                         unsigned short* __restrict__ Bfrag, int id) {
    constexpr int NS = FI / 32;
    int lane = id & 63;
    int s = (id >> 6) % NS;
    int t = (id >> 6) / NS;
    int n = t * 16 + (lane & 15);
    int kbase = s * 32 + (lane >> 4) * 8;
    int sec = n / FO;        // 0 -> W2, 1 -> W1, 2 -> W0 - W2
    int nc  = n % FO;
    ushort8_t out;
#pragma unroll
    for (int j = 0; j < 8; j++) {
        int k = kbase + j;
        float v;
        if (sec == 0)      v = W[(size_t)(2 * FI + k) * FO + nc];
        else if (sec == 1) v = W[(size_t)(1 * FI + k) * FO + nc];
        else               v = W[(size_t)(0 * FI + k) * FO + nc]
                             - W[(size_t)(2 * FI + k) * FO + nc];
        out[j] = f2bf(v);
    }
    *(ushort8_t*)(Bfrag + (size_t)id * 8) = out;
}

// Separate launch, stream-ordered BEFORE any consumer of Bf1/2/3 (R13 race lesson).
__global__ void prepB_all_kernel(const float* __restrict__ W1, const float* __restrict__ W2,
                                 const float* __restrict__ W3,
                                 unsigned short* __restrict__ Bf1,
                                 unsigned short* __restrict__ Bf2,
                                 unsigned short* __restrict__ Bf3) {
    int id = blockIdx.x * blockDim.x + threadIdx.x;
    if (id < 3072)      prep_one<128, 64>(W1, Bf1, id);            // 12*4*64
    else if (id < 3840) prep_one<64, 32>(W2, Bf2, id - 3072);      //  6*2*64
    else if (id < 4032) prep_one<32, 16>(W3, Bf3, id - 3840);      //  3*1*64
}

// ---- fused1: interleaved [scatter | gemm layer-1], NO LDS ----
__global__ __launch_bounds__(256) void fused1_kernel(
        const int* __restrict__ src, const int* __restrict__ dst,
        int* __restrict__ fill, int* __restrict__ deg_o, int* __restrict__ col,
        const unsigned short* __restrict__ Bf1,
        const float* __restrict__ x, unsigned short* __restrict__ Tbf,
        unsigned short* __restrict__ Sbf, unsigned short* __restrict__ Ubf,
        int E, int N) {
    const int g = blockIdx.x / 9;
    const int r = blockIdx.x % 9;
    if (r < 4) {
        // ------- scatter: 2 edges/thread (R15-proven) -------
        int sid = g * 4 + r;
        if (sid >= NB_SCAT) return;
        int e0 = (sid * 256 + threadIdx.x) * 2;
#pragma unroll
        for (int q = 0; q < 2; q++) {
            int e = e0 + q;
            if (e < E) {
                int s = src[e], d = dst[e];
                if (s != d) {
                    atomicAdd(&deg_o[s], 1);
                    int pos = atomicAdd(&fill[d], 1) & (CAP - 1);   // wrap guard
                    col[(size_t)d * CAP + pos] = s;
                }
            }
        }
        return;
    }
    // ------- gemm layer-1 path (direct-global B, latency hides in atomic shadow) -------
    int gblk = g * 5 + (r - 4);
    if (gblk >= NB_G1) return;
    constexpr int NT = 12;   // 3*64/16
    constexpr int NS = 4;    // 128/32
    const int lane = threadIdx.x & 63;
    const int wave = threadIdx.x >> 6;
    const int m0   = gblk * 64 + wave * 16;
    const int quad = lane >> 4;
    const int mrow = m0 + (lane & 15);

    floatx4_t acc[NT];
#pragma unroll
    for (int t = 0; t < NT; t++) acc[t] = (floatx4_t){0.f, 0.f, 0.f, 0.f};

#pragma unroll
    for (int s = 0; s < NS; s++) {
        bf16x8_t a;
        if (mrow < N) {
            const float* ap = x + (size_t)mrow * 128 + s * 32 + quad * 8;
            float4 a0 = *(const float4*)(ap);
            float4 a1 = *(const float4*)(ap + 4);
            a[0] = (short)f2bf(a0.x); a[1] = (short)f2bf(a0.y);
            a[2] = (short)f2bf(a0.z); a[3] = (short)f2bf(a0.w);
            a[4] = (short)f2bf(a1.x); a[5] = (short)f2bf(a1.y);
            a[6] = (short)f2bf(a1.z); a[7] = (short)f2bf(a1.w);
        } else {
            a = (bf16x8_t){0, 0, 0, 0, 0, 0, 0, 0};
        }
#pragma unroll
        for (int t = 0; t < NT; t++) {
            bf16x8_t b = *(const bf16x8_t*)(Bf1 + ((size_t)(t * NS + s) * 64 + lane) * 8);
            acc[t] = __builtin_amdgcn_mfma_f32_16x16x32_bf16(a, b, acc[t], 0, 0, 0);
        }
    }
    // C/D layout: col = lane&15, row = quad*4 + reg   [verified m89/m91]
#pragma unroll
    for (int t = 0; t < NT; t++) {
        int n   = t * 16 + (lane & 15);
        int sec = (t * 16) / 64;
        int nc  = n % 64;
#pragma unroll
        for (int r2 = 0; r2 < 4; r2++) {
            int m = m0 + quad * 4 + r2;
            if (m >= N) continue;
            unsigned short v = f2bf(acc[t][r2]);
            size_t o = (size_t)m * 64 + nc;
            if (sec == 0)      Ubf[o] = v;
            else if (sec == 1) Tbf[o] = v;
            else               Sbf[o] = v;
        }
    }
}

// ---- rdeg: rsqrt table so props do 1 mul/edge ----
__global__ void rdeg_kernel(const int* __restrict__ deg_o, float* __restrict__ rdeg, int N) {
    int i = blockIdx.x * blockDim.x + threadIdx.x;
    if (i < N) {
        int d = deg_o[i];
        rdeg[i] = (d > 0) ? rsqrtf((float)d) : 0.0f;
    }
}

// ---- 4-deep branchless gather core (R21) ----
// col is zero-initialized: slots >= fill hold index 0 (valid row), weight is
// forced to 0 for them. Tail gathers all hit row 0 -> L1-hot, nearly free.
// Gives 4 independent gathers in flight per thread (vs 2 in R18).
#define GATHER4_LOOP(BASEPTR, WIDTH, COFF)                                        \
    for (int p = 0; p < nedge; p += 4) {                                          \
        int4 cs = *(const int4*)(col + beg + p);                                  \
        int rem = nedge - p;                                                      \
        float w0 = di * rdeg[cs.x];                                               \
        float w1 = (rem > 1) ? di * rdeg[cs.y] : 0.f;                             \
        float w2 = (rem > 2) ? di * rdeg[cs.z] : 0.f;                             \
        float w3 = (rem > 3) ? di * rdeg[cs.w] : 0.f;                             \
        ushort8_t u0 = *(const ushort8_t*)((BASEPTR) + (size_t)cs.x * (WIDTH) + (COFF)); \
        ushort8_t u1 = *(const ushort8_t*)((BASEPTR) + (size_t)cs.y * (WIDTH) + (COFF)); \
        ushort8_t u2 = *(const ushort8_t*)((BASEPTR) + (size_t)cs.z * (WIDTH) + (COFF)); \
        ushort8_t u3 = *(const ushort8_t*)((BASEPTR) + (size_t)cs.w * (WIDTH) + (COFF)); \
        _Pragma("unroll")                                                         \
        for (int j = 0; j < 8; j++) {                                             \
            acc[j] = fmaf(w0, bf2f(u0[j]), acc[j]);                               \
            acc[j] = fmaf(w1, bf2f(u1[j]), acc[j]);                               \
            acc[j] = fmaf(w2, bf2f(u2[j]), acc[j]);                               \
            acc[j] = fmaf(w3, bf2f(u3[j]), acc[j]);                               \
        }                                                                         \
    }

// ---- propA8: Obf[i] = bf16( T[i] + 2 * sum_p w(p)*Ubf[col[p]] ), 4-deep MLP ----
template <int FO>
__global__ void propA8_kernel(const unsigned short* __restrict__ Ubf,
                              const unsigned short* __restrict__ Tbf,
                              const int* __restrict__ fill, const float* __restrict__ rdeg,
                              const int* __restrict__ col,
                              unsigned short* __restrict__ Obf, int N) {
    constexpr int PER = FO / 8;
    unsigned idx = blockIdx.x * blockDim.x + threadIdx.x;
    if (idx >= (unsigned)N * PER) return;
    int i = idx / PER;
    int c = (idx & (PER - 1)) * 8;
    int beg = i * CAP;
    int nedge = min(fill[i], CAP);
    float di = -rdeg[i];
    float acc[8] = {0.f, 0.f, 0.f, 0.f, 0.f, 0.f, 0.f, 0.f};
    GATHER4_LOOP(Ubf, FO, c)
    ushort8_t tv = *(const ushort8_t*)(Tbf + (size_t)i * FO + c);
    ushort8_t o;
#pragma unroll
    for (int j = 0; j < 8; j++) o[j] = f2bf(bf2f(tv[j]) + 2.f * acc[j]);
    *(ushort8_t*)(Obf + (size_t)i * FO + c) = o;
}

// ---- propCG<FI,FO>: fused [propC layer-k epilogue -> LDS h] + [gemm FI->FO] ----
template <int FI, int FO>
__global__ __launch_bounds__(256) void propCG_kernel(
        const unsigned short* __restrict__ Bbf,   // gather source (propA out), width FI
        const unsigned short* __restrict__ Sbf,   // local S term, width FI
        const int* __restrict__ fill, const float* __restrict__ rdeg,
        const int* __restrict__ col,
        const float* __restrict__ b, const float* __restrict__ g,
        const float* __restrict__ be, const float* __restrict__ m,
        const float* __restrict__ vv,
        const unsigned short* __restrict__ Bfrag,  // FI->FO fragments
        unsigned short* __restrict__ Tout, unsigned short* __restrict__ Sout,
        unsigned short* __restrict__ Uout, int N) {
    constexpr int PER = FI / 8;
    constexpr int NT = 3 * FO / 16;
    constexpr int NS = FI / 32;
    constexpr int NFRAG = NT * NS;
    constexpr int HST = FI + 8;     // h_lds row stride (shorts)
    __shared__ ushort8_t bl[NFRAG * 64];
    __shared__ unsigned short h_lds[64 * HST];

    for (int q = threadIdx.x; q < NFRAG * 64; q += 256)
        bl[q] = ((const ushort8_t*)Bfrag)[q];

    const int m0 = blockIdx.x * 64;

    // ---- phase 1: propC for rows m0..m0+63 -> h_lds ----
    for (int w = threadIdx.x; w < 64 * PER; w += 256) {
        int ii = w / PER;
        int i  = m0 + ii;
        int c  = (w % PER) * 8;
        ushort8_t o = (ushort8_t){0, 0, 0, 0, 0, 0, 0, 0};
        if (i < N) {
            int beg = i * CAP;
            int nedge = min(fill[i], CAP);
            float di = -rdeg[i];
            float acc[8] = {0.f, 0.f, 0.f, 0.f, 0.f, 0.f, 0.f, 0.f};
            GATHER4_LOOP(Bbf, FI, c)
            ushort8_t sv = *(const ushort8_t*)(Sbf + (size_t)i * FI + c);
#pragma unroll
            for (int j = 0; j < 8; j++) {
                int f = c + j;
                float A = g[f] * rsqrtf(vv[f] + BN_EPS);
                float B = be[f] - (m[f] - b[f]) * A;
                float y = (bf2f(sv[j]) + acc[j]) * A + B;
                y = y > 0.0f ? y : 0.01f * y;
                o[j] = f2bf(y);
            }
        }
        *(ushort8_t*)&h_lds[ii * HST + c] = o;
    }
    __syncthreads();

    // ---- phase 2: gemm FI->FO, A from h_lds ----
    const int lane = threadIdx.x & 63;
    const int wave = threadIdx.x >> 6;
    const int quad = lane >> 4;
    const int mloc = wave * 16 + (lane & 15);

    floatx4_t acc[NT];
#pragma unroll
    for (int t = 0; t < NT; t++) acc[t] = (floatx4_t){0.f, 0.f, 0.f, 0.f};

#pragma unroll
    for (int s = 0; s < NS; s++) {
        bf16x8_t a = *(const bf16x8_t*)&h_lds[mloc * HST + s * 32 + quad * 8];
#pragma unroll
        for (int t = 0; t < NT; t++) {
            bf16x8_t bfr = *(const bf16x8_t*)&bl[(t * NS + s) * 64 + lane];
            acc[t] = __builtin_amdgcn_mfma_f32_16x16x32_bf16(a, bfr, acc[t], 0, 0, 0);
        }
    }
#pragma unroll
    for (int t = 0; t < NT; t++) {
        int n   = t * 16 + (lane & 15);
        int sec = (t * 16) / FO;
        int nc  = n % FO;
#pragma unroll
        for (int r = 0; r < 4; r++) {
            int mm = m0 + wave * 16 + quad * 4 + r;
            if (mm >= N) continue;
            unsigned short v = f2bf(acc[t][r]);
            size_t o = (size_t)mm * FO + nc;
            if (sec == 0)      Uout[o] = v;
            else if (sec == 1) Tout[o] = v;
            else               Sout[o] = v;
        }
    }
}

// ---- poolC: fused [propC layer-3 (w16) -> LDS h3] + [mean pool] ----
__global__ __launch_bounds__(256) void poolC_kernel(
        const unsigned short* __restrict__ Bbf,   // propA<16> output
        const unsigned short* __restrict__ Sbf,   // S3
        const int* __restrict__ fill, const float* __restrict__ rdeg,
        const int* __restrict__ col,
        const float* __restrict__ b, const float* __restrict__ g,
        const float* __restrict__ be, const float* __restrict__ m,
        const float* __restrict__ vv,
        const int* __restrict__ batch,
        float* __restrict__ pool, float* __restrict__ cnt, int N) {
    __shared__ unsigned short h_lds[PNPB * 16];   // 8 KB
    __shared__ float sp[NG * 16];
    __shared__ float sc[NG];
    const int t = threadIdx.x;
    for (int i = t; i < NG * 16; i += 256) sp[i] = 0.f;
    for (int i = t; i < NG; i += 256) sc[i] = 0.f;

    const int base = blockIdx.x * PNPB;
    // ---- phase 1: propC<16> for rows base..base+255 -> h_lds ----
    for (int w = t; w < PNPB * 2; w += 256) {
        int ii = w >> 1;
        int i  = base + ii;
        int c  = (w & 1) * 8;
        ushort8_t o = (ushort8_t){0, 0, 0, 0, 0, 0, 0, 0};
        if (i < N) {
            int beg = i * CAP;
            int nedge = min(fill[i], CAP);
            float di = -rdeg[i];
            float acc[8] = {0.f, 0.f, 0.f, 0.f, 0.f, 0.f, 0.f, 0.f};
            GATHER4_LOOP(Bbf, 16, c)
            ushort8_t sv = *(const ushort8_t*)(Sbf + (size_t)i * 16 + c);
#pragma unroll
            for (int j = 0; j < 8; j++) {
                int f = c + j;
                float A = g[f] * rsqrtf(vv[f] + BN_EPS);
                float B = be[f] - (m[f] - b[f]) * A;
                float y = (bf2f(sv[j]) + acc[j]) * A + B;
                y = y > 0.0f ? y : 0.01f * y;
                o[j] = f2bf(y);
            }
        }
        *(ushort8_t*)&h_lds[ii * 16 + c] = o;
    }
    __syncthreads();

    // ---- phase 2: pool from LDS ----
    const int f4 = (t & 3) * 4;      // feature quad
    const int nl = t >> 2;           // node lane 0..63
    const int nEnd = min(base + PNPB, N);
    float4 acc = make_float4(0.f, 0.f, 0.f, 0.f);
    float cacc = 0.f;
    int gcur = -1;
    for (int n = base + nl; n < nEnd; n += 64) {
        int gi = batch[n];
        if (gi != gcur) {
            if (gcur >= 0) {
                atomicAdd(&sp[gcur * 16 + f4 + 0], acc.x);
                atomicAdd(&sp[gcur * 16 + f4 + 1], acc.y);
                atomicAdd(&sp[gcur * 16 + f4 + 2], acc.z);
                atomicAdd(&sp[gcur * 16 + f4 + 3], acc.w);
                if (f4 == 0) atomicAdd(&sc[gcur], cacc);
            }
            gcur = gi; acc = make_float4(0.f, 0.f, 0.f, 0.f); cacc = 0.f;
        }
        ushort4_t hv = *(const ushort4_t*)&h_lds[(n - base) * 16 + f4];
        acc.x += bf2f(hv.x); acc.y += bf2f(hv.y);
        acc.z += bf2f(hv.z); acc.w += bf2f(hv.w);
        cacc += 1.f;
    }
    if (gcur >= 0) {
        atomicAdd(&sp[gcur * 16 + f4 + 0], acc.x);
        atomicAdd(&sp[gcur * 16 + f4 + 1], acc.y);
        atomicAdd(&sp[gcur * 16 + f4 + 2], acc.z);
        atomicAdd(&sp[gcur * 16 + f4 + 3], acc.w);
        if (f4 == 0) atomicAdd(&sc[gcur], cacc);
    }
    __syncthreads();
    for (int i = t; i < NG * 16; i += 256)
        if (sp[i] != 0.f) unsafeAtomicAdd(&pool[i], sp[i]);
    for (int i = t; i < NG; i += 256)
        if (sc[i] != 0.f) unsafeAtomicAdd(&cnt[i], sc[i]);
}

// ---------------- final linear head ----------------
__global__ void final_kernel(const float* __restrict__ pool, const float* __restrict__ cnt,
                             const float* __restrict__ lw, const float* __restrict__ lb,
                             float* __restrict__ out) {
    int idx = threadIdx.x;
    if (idx >= NG * 2) return;
    int g = idx >> 1;
    int c = idx & 1;
    float inv = 1.0f / fmaxf(cnt[g], 1.0f);
    float acc = 0.0f;
#pragma unroll
    for (int f = 0; f < 16; f++) acc += pool[g * 16 + f] * lw[c * 16 + f];
    out[idx] = acc * inv + lb[c];
}

extern "C" void kernel_launch(void* const* d_in, const int* in_sizes, int n_in,
                              void* d_out, int out_size, void* d_ws, size_t ws_size,
                              hipStream_t stream) {
    const float* x    = (const float*)d_in[0];
    const int*   ei   = (const int*)d_in[1];
    const int*   batch= (const int*)d_in[2];
    const float* W1 = (const float*)d_in[3];
    const float* b1 = (const float*)d_in[4];
    const float* g1 = (const float*)d_in[5];
    const float* be1= (const float*)d_in[6];
    const float* m1 = (const float*)d_in[7];
    const float* v1 = (const float*)d_in[8];
    const float* W2 = (const float*)d_in[9];
    const float* b2 = (const float*)d_in[10];
    const float* g2 = (const float*)d_in[11];
    const float* be2= (const float*)d_in[12];
    const float* m2 = (const float*)d_in[13];
    const float* v2 = (const float*)d_in[14];
    const float* W3 = (const float*)d_in[15];
    const float* b3 = (const float*)d_in[16];
    const float* g3 = (const float*)d_in[17];
    const float* be3= (const float*)d_in[18];
    const float* m3 = (const float*)d_in[19];
    const float* v3 = (const float*)d_in[20];
    const float* lw = (const float*)d_in[21];
    const float* lb = (const float*)d_in[22];

    const int* src = ei;            // edge_index[0]
    const int* dst = ei + NE;       // edge_index[1]

    float* ws = (float*)d_ws;
    // ---- workspace layout (4-byte units, 16B-aligned; ~62 MB total) ----
    // col moved INSIDE the zeroed prefix (R21): zero-init makes 4-wide slot
    // loads past fill[] safe (index 0, weight forced to 0).
    size_t off = 0;
    int*   fill  = (int*)(ws + off); off += NN;    // in-degree / slot counters
    int*   deg_o = (int*)(ws + off); off += NN;    // out-degree
    float* pool  = ws + off; off += NG * 16;
    float* cnt   = ws + off; off += NG;
    int*   col   = (int*)(ws + off); off += (size_t)NN * CAP;  // fixed-stride CSR cols
    size_t zero_bytes = off * sizeof(float);       // one memset covers all of the above
    float* rdeg  = ws + off; off += NN;            // rsqrt(deg_o) table
    unsigned short* Tbf  = (unsigned short*)(ws + off); off += (size_t)NN * 32;  // NN*64 bf16
    unsigned short* Ubf  = (unsigned short*)(ws + off); off += (size_t)NN * 32;
    unsigned short* Bbbf = (unsigned short*)(ws + off); off += (size_t)NN * 32;
    unsigned short* S1bf = (unsigned short*)(ws + off); off += (size_t)NN * 32;  // S1 (w64)
    unsigned short* S2bf = (unsigned short*)(ws + off); off += (size_t)NN * 16;  // S2 (w32)
    unsigned short* S3bf = (unsigned short*)(ws + off); off += (size_t)NN * 8;   // S3 (w16)
    unsigned short* Bf1  = (unsigned short*)(ws + off); off += 12288;  // 24576 bf16
    unsigned short* Bf2  = (unsigned short*)(ws + off); off += 3072;   //  6144 bf16
    unsigned short* Bf3  = (unsigned short*)(ws + off); off += 768;    //  1536 bf16

    hipMemsetAsync(ws, 0, zero_bytes, stream);

    // ---- prepB first (stream-ordered: Bf1 complete before fused1's gemm blocks) ----
    prepB_all_kernel<<<16, BS, 0, stream>>>(W1, W2, W3, Bf1, Bf2, Bf3);

    // ---- fused: interleaved CSR scatter + gemm layer-1 ----
    fused1_kernel<<<NB_F1, 256, 0, stream>>>(
        src, dst, fill, deg_o, col, Bf1, x, Tbf, S1bf, Ubf, NE, NN);

    // ---- rsqrt(deg) table ----
    rdeg_kernel<<<cdiv(NN, BS), BS, 0, stream>>>(deg_o, rdeg, NN);

    // ---- layer 1 propA, then fused [propC1 + gemm2] ----
    propA8_kernel<64><<<cdiv((long long)NN * 8, BS), BS, 0, stream>>>(Ubf, Tbf, fill, rdeg,
                                                                      col, Bbbf, NN);
    propCG_kernel<64, 32><<<cdiv(NN, 64), 256, 0, stream>>>(
        Bbbf, S1bf, fill, rdeg, col, b1, g1, be1, m1, v1,
        Bf2, Tbf, S2bf, Ubf, NN);

    // ---- layer 2 propA, then fused [propC2 + gemm3] ----
    propA8_kernel<32><<<cdiv((long long)NN * 4, BS), BS, 0, stream>>>(Ubf, Tbf, fill, rdeg,
                                                                      col, Bbbf, NN);
    propCG_kernel<32, 16><<<cdiv(NN, 64), 256, 0, stream>>>(
        Bbbf, S2bf, fill, rdeg, col, b2, g2, be2, m2, v2,
        Bf3, Tbf, S3bf, Ubf, NN);

    // ---- layer 3 propA, then fused [propC3 + pool] ----
    propA8_kernel<16><<<cdiv((long long)NN * 2, BS), BS, 0, stream>>>(Ubf, Tbf, fill, rdeg,
                                                                      col, Bbbf, NN);
    poolC_kernel<<<cdiv(NN, PNPB), 256, 0, stream>>>(
        Bbbf, S3bf, fill, rdeg, col, b3, g3, be3, m3, v3,
        batch, pool, cnt, NN);

    // ---- head ----
    final_kernel<<<1, 128, 0, stream>>>(pool, cnt, lw, lb, (float*)d_out);
}